// Round 6
// baseline (567.584 us; speedup 1.0000x reference)
//
#include <hip/hip_runtime.h>
#include <cstdint>
#include <cstddef>

// OVOLinearSemanticExtractor (last_only=1) — exact fp32 replication.
// R10: fuse_vote weight path fixed. R9 evidence: VALU-issue ~11.5k inst/thread
// (~2x algorithmic need) + 57MB residual scratch -> the per-c W3T loads were
// per-lane vector global_loads (uniformity not proven for __device__ global +
// runtime c), not s_loads. Fix: stage w3 into LDS once per block, transposed
// [c][68] (16B-aligned rows), read per c as 17 broadcast ds_read_b128
// (uniform addr -> conflict-free, immediate offsets). xr[64] hoisted;
// acc[66] compile-time indexed; __launch_bounds__(256,2) -> ~256 reg budget
// (acc66+xr64+wv68+taps ~= 230, no spill). LDS 57.5KB -> 2 blocks/CU:
// fine, kernel is issue-bound not latency-bound. W3T global + conv_all
// transpose block deleted. Per-o FMA chains keep exact ascending-c order.

#define N_BATCH 8
#define N_OVO   66
#define N_CLS   12

__constant__ unsigned char PAIR_I[N_OVO] = {
  0,0,0,0,0,0,0,0,0,0,0,
  1,1,1,1,1,1,1,1,1,1,
  2,2,2,2,2,2,2,2,2,
  3,3,3,3,3,3,3,3,
  4,4,4,4,4,4,4,
  5,5,5,5,5,5,
  6,6,6,6,6,
  7,7,7,7,
  8,8,8,
  9,9,
  10
};
__constant__ unsigned char PAIR_J[N_OVO] = {
  1,2,3,4,5,6,7,8,9,10,11,
  2,3,4,5,6,7,8,9,10,11,
  3,4,5,6,7,8,9,10,11,
  4,5,6,7,8,9,10,11,
  5,6,7,8,9,10,11,
  6,7,8,9,10,11,
  7,8,9,10,11,
  8,9,10,11,
  9,10,11,
  10,11,
  11
};

// ---------------------------------------------------------------------------
// og-split conv 1x1 body (proven): 256 px/block, OG=11 outputs per thread,
// scalar (SGPR) weights, strict ascending-c fp32 FMA chain. Writes [n][p][66].
// ---------------------------------------------------------------------------
template<int C, int S2, int OG>
__device__ __forceinline__
void conv_body(int b, const float* __restrict__ x, const float* __restrict__ w,
               const float* __restrict__ bias, float* __restrict__ out)
{
    constexpr int NOG = N_OVO / OG;          // 6
    constexpr int PX  = S2 / 256;
    const int og  = b % NOG;                 // fastest -> L2 x-window reuse
    int rest      = b / NOG;
    const int pxb = rest % PX;
    const int n   = rest / PX;
    const int o0  = og * OG;                 // block-uniform -> scalar weights
    const int p   = pxb * 256 + threadIdx.x;

    float acc[OG];
#pragma unroll
    for (int oi = 0; oi < OG; ++oi) acc[oi] = 0.0f;

    const float* xb = x + (size_t)n * C * S2 + p;
    for (int c0 = 0; c0 < C; c0 += 8) {
        float xr[8];
#pragma unroll
        for (int k = 0; k < 8; ++k)
            xr[k] = xb[(size_t)(c0 + k) * S2];
#pragma unroll
        for (int oi = 0; oi < OG; ++oi) {
            const float* wrow = w + (size_t)(o0 + oi) * C + c0;
#pragma unroll
            for (int k = 0; k < 8; ++k)
                acc[oi] = __fmaf_rn(wrow[k], xr[k], acc[oi]);
        }
    }

    float* op = out + ((size_t)n * S2 + p) * N_OVO + o0;
#pragma unroll
    for (int oi = 0; oi < OG; ++oi)
        op[oi] = __fadd_rn(acc[oi], bias[o0 + oi]);
}

// Merged conv dispatch.
#define B0 192
#define B1 768
#define B2 3072

__global__ __launch_bounds__(256)
void conv_all(const float* __restrict__ x0, const float* __restrict__ w0,
              const float* __restrict__ b0, float* __restrict__ c0,
              const float* __restrict__ x1, const float* __restrict__ w1,
              const float* __restrict__ b1, float* __restrict__ c1,
              const float* __restrict__ x2, const float* __restrict__ w2,
              const float* __restrict__ b2, float* __restrict__ c2)
{
    const int bid = blockIdx.x;
    if (bid < B0) {
        conv_body<512, 1024, 11>(bid, x0, w0, b0, c0);
    } else if (bid < B0 + B1) {
        conv_body<256, 4096, 11>(bid - B0, x1, w1, b1, c1);
    } else {
        conv_body<128, 16384, 11>(bid - (B0 + B1), x2, w2, b2, c2);
    }
}

// ---------------------------------------------------------------------------
// Fused stage.
// ---------------------------------------------------------------------------
#define WT0 4
#define WT1 6
#define WT2 10
#define WROW 68   // LDS row stride for transposed weights: 68*4=272 B, %16==0

// Tile LDS layout (RELS = WT*WT):
//   o in [0,64): 16B slot index = (o>>2)*RELS + swz(rel), element (o&3)
//     with swz(rel) = rel ^ ((rel>>3)&3)
//   o in {64,65}: float2 tail at 64*RELS + rel*2 + (o-64)

template<int WT, int SS>
__device__ __forceinline__ void stage_tile(float* __restrict__ t,
                                           const float* __restrict__ src,
                                           int y0, int x0)
{
    constexpr int RELS = WT * WT;
    for (int idx = threadIdx.x; idx < RELS * 33; idx += 256) {
        int r  = idx / 33;
        int k  = idx - r * 33;          // float2 index over o: o = 2k, 2k+1
        int ry = r / WT, rx = r - ry * WT;
        int sy = min(max(y0 + ry, 0), SS - 1);
        int sx = min(max(x0 + rx, 0), SS - 1);
        const float2 v = *reinterpret_cast<const float2*>(
            src + ((size_t)sy * SS + sx) * N_OVO + 2 * k);
        int dst;
        if (k < 32) {
            int sr = r ^ ((r >> 3) & 3);
            dst = ((k >> 1) * RELS + sr) * 4 + (k & 1) * 2;
        } else {
            dst = 64 * RELS + r * 2;
        }
        *reinterpret_cast<float2*>(t + dst) = v;
    }
}

__device__ __forceinline__ float bil1(float v00, float v01, float v10, float v11,
                                      float wy, float wy0, float wx, float wx0,
                                      int ysing, int xsing)
{
    float u0 = ysing ? v00 : __fmaf_rn(wy, v10, __fmul_rn(wy0, v00));
    float u1 = ysing ? v01 : __fmaf_rn(wy, v11, __fmul_rn(wy0, v01));
    return xsing ? u0 : __fmaf_rn(wx, u1, __fmul_rn(wx0, u0));
}

template<int RELS>
__device__ __forceinline__ float4 bil4(const float* __restrict__ t, int g,
                                       int s00, int s01, int s10, int s11,
                                       float wy, float wx, int ysing, int xsing)
{
    const float* base = t + g * (RELS * 4);
    float4 v00 = *reinterpret_cast<const float4*>(base + s00 * 4);
    float4 v01 = *reinterpret_cast<const float4*>(base + s01 * 4);
    float4 v10 = *reinterpret_cast<const float4*>(base + s10 * 4);
    float4 v11 = *reinterpret_cast<const float4*>(base + s11 * 4);
    float wy0 = 1.0f - wy, wx0 = 1.0f - wx;
    float4 r;
    r.x = bil1(v00.x, v01.x, v10.x, v11.x, wy, wy0, wx, wx0, ysing, xsing);
    r.y = bil1(v00.y, v01.y, v10.y, v11.y, wy, wy0, wx, wx0, ysing, xsing);
    r.z = bil1(v00.z, v01.z, v10.z, v11.z, wy, wy0, wx, wx0, ysing, xsing);
    r.w = bil1(v00.w, v01.w, v10.w, v11.w, wy, wy0, wx, wx0, ysing, xsing);
    return r;
}

__global__ __launch_bounds__(256, 2)   // ~256 reg budget: acc66+xr64+wv68 fits
void fuse_vote(const float* __restrict__ x3, const float* __restrict__ w3,
               const float* __restrict__ b3,
               const float* __restrict__ c0buf, const float* __restrict__ c1buf,
               const float* __restrict__ c2buf,
               float* __restrict__ out)
{
    const int n  = blockIdx.z;
    const int tx = threadIdx.x & 15, ty = threadIdx.x >> 4;
    const int X0 = blockIdx.x * 16,  Y0 = blockIdx.y * 16;
    const int X  = X0 + tx,          Y  = Y0 + ty;

    __shared__ alignas(16) float t0s[16  * N_OVO];
    __shared__ alignas(16) float t1s[36  * N_OVO];
    __shared__ alignas(16) float t2s[100 * N_OVO];
    __shared__ alignas(16) float wlds[64 * WROW];   // transposed w3 [c][68]
    // total LDS = 40128 + 17408 = 57536 B -> 2 blocks/CU

    // ---- per-thread taps (identical float math to the passing kernel) ----
    int rel00[3], rel01[3], rel10[3], rel11[3], ysing[3], xsing[3];
    int s00[3], s01[3], s10[3], s11[3];               // swizzled slots
    float wxv[3], wyv[3];
    int x0raw[3], y0raw[3];
    const int   Ss[3]   = {32, 64, 128};
    const float invs[3] = {32.0f / 256.0f, 64.0f / 256.0f, 128.0f / 256.0f};
    const int   Wt[3]   = {WT0, WT1, WT2};
#pragma unroll
    for (int s = 0; s < 3; ++s) {
        float inv = invs[s];
        int S = Ss[s];
        x0raw[s] = (int)floorf(((float)X0 + 0.5f) * inv - 0.5f);
        y0raw[s] = (int)floorf(((float)Y0 + 0.5f) * inv - 0.5f);
        float fx = ((float)X + 0.5f) * inv - 0.5f;
        float fy = ((float)Y + 0.5f) * inv - 0.5f;
        int ix0 = (int)floorf(fx), iy0 = (int)floorf(fy);
        wxv[s] = fx - (float)ix0;  wyv[s] = fy - (float)iy0;
        xsing[s] = (ix0 < 0) || (ix0 + 1 > S - 1);
        ysing[s] = (iy0 < 0) || (iy0 + 1 > S - 1);
        int rx = ix0 - x0raw[s], ry = iy0 - y0raw[s];
        rel00[s] = ry * Wt[s] + rx;
        rel01[s] = rel00[s] + 1;
        rel10[s] = rel00[s] + Wt[s];
        rel11[s] = rel10[s] + 1;
        s00[s] = rel00[s] ^ ((rel00[s] >> 3) & 3);
        s01[s] = rel01[s] ^ ((rel01[s] >> 3) & 3);
        s10[s] = rel10[s] ^ ((rel10[s] >> 3) & 3);
        s11[s] = rel11[s] ^ ((rel11[s] >> 3) & 3);
    }

    // ---- stage transposed weights: w3 [66][64] -> wlds [c][68] ----
    for (int idx = threadIdx.x; idx < 64 * N_OVO; idx += 256) {
        int o = idx >> 6, c = idx & 63;     // contiguous global read
        wlds[c * WROW + o] = w3[idx];
    }

    // ---- cooperative tile staging ----
    stage_tile<WT0, 32 >(t0s, c0buf + (size_t)n * 1024  * N_OVO, y0raw[0], x0raw[0]);
    stage_tile<WT1, 64 >(t1s, c1buf + (size_t)n * 4096  * N_OVO, y0raw[1], x0raw[1]);
    stage_tile<WT2, 128>(t2s, c2buf + (size_t)n * 16384 * N_OVO, y0raw[2], x0raw[2]);

    // ---- hoist stage3 channel column (global latency overlaps staging) ----
    float xr[64];
    {
        const float* xp = x3 + (size_t)n * 64 * 65536 + (size_t)Y * 256 + X;
#pragma unroll
        for (int c = 0; c < 64; ++c) xr[c] = xp[(size_t)c * 65536];
    }

    __syncthreads();   // wlds + tiles ready; xr drained here too

    // ---- phase A: stage3 conv, c-outer, acc[66], broadcast b128 weights ----
    // Each o's chain is ascending-c with init 0 -> bit-exact.
    float acc[N_OVO];
#pragma unroll
    for (int o = 0; o < N_OVO; ++o) acc[o] = 0.0f;

#pragma unroll 1
    for (int c = 0; c < 64; ++c) {
        const float* wrow = &wlds[c * WROW];
        float wv[68];
#pragma unroll
        for (int q = 0; q < 17; ++q)
            *reinterpret_cast<float4*>(&wv[4 * q]) =
                *reinterpret_cast<const float4*>(wrow + 4 * q);
        float xv = xr[c];
#pragma unroll
        for (int o = 0; o < N_OVO; ++o)
            acc[o] = __fmaf_rn(wv[o], xv, acc[o]);
    }

    unsigned long long packed = 0;   // 12 classes x 4-bit counts (max 11)

#pragma unroll
    for (int g = 0; g < 16; ++g) {
        const int o = g * 4;
        float4 L3;
        L3.x = __fadd_rn(acc[o],     b3[o]);
        L3.y = __fadd_rn(acc[o + 1], b3[o + 1]);
        L3.z = __fadd_rn(acc[o + 2], b3[o + 2]);
        L3.w = __fadd_rn(acc[o + 3], b3[o + 3]);

        float4 s0 = bil4<16 >(t0s, g, s00[0], s01[0], s10[0], s11[0],
                              wyv[0], wxv[0], ysing[0], xsing[0]);
        float4 s1 = bil4<36 >(t1s, g, s00[1], s01[1], s10[1], s11[1],
                              wyv[1], wxv[1], ysing[1], xsing[1]);
        float4 s2 = bil4<100>(t2s, g, s00[2], s01[2], s10[2], s11[2],
                              wyv[2], wxv[2], ysing[2], xsing[2]);

        // reference order: ((L0 + L1) + L2) + L3
        float v0 = __fadd_rn(__fadd_rn(__fadd_rn(s0.x, s1.x), s2.x), L3.x);
        float v1 = __fadd_rn(__fadd_rn(__fadd_rn(s0.y, s1.y), s2.y), L3.y);
        float v2 = __fadd_rn(__fadd_rn(__fadd_rn(s0.z, s1.z), s2.z), L3.z);
        float v3 = __fadd_rn(__fadd_rn(__fadd_rn(s0.w, s1.w), s2.w), L3.w);

        packed += (v0 > 0.0f) ? (1ull << (4 * (int)PAIR_I[o]))
                              : (1ull << (4 * (int)PAIR_J[o]));
        packed += (v1 > 0.0f) ? (1ull << (4 * (int)PAIR_I[o + 1]))
                              : (1ull << (4 * (int)PAIR_J[o + 1]));
        packed += (v2 > 0.0f) ? (1ull << (4 * (int)PAIR_I[o + 2]))
                              : (1ull << (4 * (int)PAIR_J[o + 2]));
        packed += (v3 > 0.0f) ? (1ull << (4 * (int)PAIR_I[o + 3]))
                              : (1ull << (4 * (int)PAIR_J[o + 3]));
    }

    // tail: o = 64, 65 (float2 region, unswizzled rel)
    {
        float L3a = __fadd_rn(acc[64], b3[64]);
        float L3b = __fadd_rn(acc[65], b3[65]);

        float La[3], Lb[3];
#pragma unroll
        for (int s = 0; s < 3; ++s) {
            const float* t = (s == 0) ? t0s : (s == 1) ? t1s : t2s;
            const int RELS = Wt[s] * Wt[s];
            const float* tb = t + 64 * RELS;
            float2 v00 = *reinterpret_cast<const float2*>(tb + rel00[s] * 2);
            float2 v01 = *reinterpret_cast<const float2*>(tb + rel01[s] * 2);
            float2 v10 = *reinterpret_cast<const float2*>(tb + rel10[s] * 2);
            float2 v11 = *reinterpret_cast<const float2*>(tb + rel11[s] * 2);
            float wy = wyv[s], wx = wxv[s];
            float wy0 = 1.0f - wy, wx0 = 1.0f - wx;
            La[s] = bil1(v00.x, v01.x, v10.x, v11.x, wy, wy0, wx, wx0, ysing[s], xsing[s]);
            Lb[s] = bil1(v00.y, v01.y, v10.y, v11.y, wy, wy0, wx, wx0, ysing[s], xsing[s]);
        }
        float ta = __fadd_rn(__fadd_rn(__fadd_rn(La[0], La[1]), La[2]), L3a);
        float tb = __fadd_rn(__fadd_rn(__fadd_rn(Lb[0], Lb[1]), Lb[2]), L3b);
        packed += (ta > 0.0f) ? (1ull << (4 * (int)PAIR_I[64]))
                              : (1ull << (4 * (int)PAIR_J[64]));
        packed += (tb > 0.0f) ? (1ull << (4 * (int)PAIR_I[65]))
                              : (1ull << (4 * (int)PAIR_J[65]));
    }

    float* op = out + (size_t)n * N_CLS * 65536 + (size_t)Y * 256 + X;
#pragma unroll
    for (int k = 0; k < N_CLS; ++k)
        op[(size_t)k * 65536] = (float)(int)((packed >> (4 * k)) & 15ull);
}

// ---------------------------------------------------------------------------
extern "C" void kernel_launch(void* const* d_in, const int* in_sizes, int n_in,
                              void* d_out, int out_size, void* d_ws, size_t ws_size,
                              hipStream_t stream)
{
    const float* stage0 = (const float*)d_in[0];
    const float* w0     = (const float*)d_in[1];
    const float* b0     = (const float*)d_in[2];
    const float* stage1 = (const float*)d_in[3];
    const float* w1     = (const float*)d_in[4];
    const float* b1     = (const float*)d_in[5];
    const float* stage2 = (const float*)d_in[6];
    const float* w2     = (const float*)d_in[7];
    const float* b2     = (const float*)d_in[8];
    const float* stage3 = (const float*)d_in[9];
    const float* w3     = (const float*)d_in[10];
    const float* b3     = (const float*)d_in[11];
    float* out = (float*)d_out;

    // fp32 workspace, layout [n][pixel][66] — EXACTLY the proven 45.4 MB:
    // c0 8*1024*66, c1 8*4096*66, c2 8*16384*66.
    float* c0 = (float*)d_ws;
    float* c1 = c0 + (size_t)540672;
    float* c2 = c1 + (size_t)2162688;

    // merged conv launch: 192 + 768 + 3072 = 4032 blocks co-scheduled
    conv_all<<<dim3(B0 + B1 + B2), 256, 0, stream>>>(
        stage0, w0, b0, c0,
        stage1, w1, b1, c1,
        stage2, w2, b2, c2);

    fuse_vote<<<dim3(16, 16, N_BATCH), 256, 0, stream>>>(stage3, w3, b3, c0, c1, c2, out);
}